// Round 1
// baseline (323.928 us; speedup 1.0000x reference)
//
#include <hip/hip_runtime.h>
#include <hip/hip_cooperative_groups.h>
#include <math.h>

namespace cg = cooperative_groups;

#define BB 16
#define TT 2048
#define FF 512

#define GRID   1024            // 4 blocks/CU x 256 CUs -> co-resident at launch_bounds(256,4)
#define NWAVES (GRID * 4)      // 4096 waves, 8 rows each -> 32768 = B*T rows

#define ACTIVE_UNITS 4096      // 256 units/batch x 16, 4 waves/unit, rows j<1024
#define ZERO_UNITS   1024      // rows j in [1024,2048): always zero (counts <= 1024)
#define MASK_UNITS   32
#define TOTAL_UNITS  (ACTIVE_UNITS + ZERO_UNITS + MASK_UNITS)

typedef float v4f __attribute__((ext_vector_type(4)));

// Single cooperative kernel: phase1 wt -> grid.sync -> phase2 seg -> grid.sync -> phase3 pool.
// Phase bodies are numerically identical to the verified 3-kernel version (same expf, same
// accumulation order); only the scheduling/launch structure changed.
__global__ __launch_bounds__(256, 4) void fused_kernel(
    const float* __restrict__ x,
    const float* __restrict__ w,
    const float* __restrict__ bias,
    const int*   __restrict__ seq_len,
    float* __restrict__ wt,
    int*   __restrict__ starts,
    int*   __restrict__ ends,
    int*   __restrict__ counts,
    float* __restrict__ out,
    float* __restrict__ mask_out)
{
    cg::grid_group grid = cg::this_grid();
    __shared__ int wsum[4];

    int tid  = threadIdx.x;
    int lane = tid & 63;
    int wv   = tid >> 6;

    // ---- Phase 1: wt[row] = sigmoid(dot(x[row,:], w) + b). One wave per row, 8 rows/wave.
    {
        int wgid = blockIdx.x * 4 + wv;             // 0..4095
        const float* wp = w + lane * 8;
        float4 w0 = *(const float4*)wp;             // w loaded once, reused for all 8 rows
        float4 w1 = *(const float4*)(wp + 4);
        float bz = bias[0];
#pragma unroll
        for (int i = 0; i < 8; ++i) {
            int row = wgid + i * NWAVES;            // 0..32767
            const float* xr = x + (size_t)row * FF + lane * 8;
            float4 a0 = *(const float4*)xr;
            float4 a1 = *(const float4*)(xr + 4);
            float s = a0.x * w0.x + a0.y * w0.y + a0.z * w0.z + a0.w * w0.w
                    + a1.x * w1.x + a1.y * w1.y + a1.z * w1.z + a1.w * w1.w;
#pragma unroll
            for (int off = 32; off > 0; off >>= 1) s += __shfl_xor(s, off, 64);
            if (lane == 0) {
                float z = s + bz;
                wt[row] = 1.0f / (1.0f + expf(-z));
            }
        }
    }

    grid.sync();

    // ---- Phase 2: per-batch valley segmentation. Blocks 0..15, 256 threads, 8 pos/thread.
    if (blockIdx.x < BB) {
        int b = blockIdx.x;
        const float* wrow = wt + b * TT;
        int t0 = tid * 8;
        float v[8];
        float4 f0 = *(const float4*)(wrow + t0);
        float4 f1 = *(const float4*)(wrow + t0 + 4);
        v[0] = f0.x; v[1] = f0.y; v[2] = f0.z; v[3] = f0.w;
        v[4] = f1.x; v[5] = f1.y; v[6] = f1.z; v[7] = f1.w;
        float left  = (tid > 0)   ? wrow[t0 - 1] : 0.f;   // t=0 excluded by t>0 check anyway
        float right = (tid < 255) ? wrow[t0 + 8] : 0.f;   // t=T-1 excluded by t<T-1 check
        unsigned int flags = 0;
#pragma unroll
        for (int k = 0; k < 8; ++k) {
            int t = t0 + k;
            float prev = (k == 0) ? left  : v[k - 1];
            float next = (k == 7) ? right : v[k + 1];
            bool val = (t > 0) && (t < TT - 1) && (v[k] < prev) && (v[k] < next);
            if (val) flags |= (1u << k);
        }
        int cnt = __popc(flags);
        int inc = cnt;
#pragma unroll
        for (int off = 1; off < 64; off <<= 1) {
            int y = __shfl_up(inc, off, 64);
            if (lane >= off) inc += y;
        }
        if (lane == 63) wsum[wv] = inc;
        __syncthreads();
        int waveOff = 0;
#pragma unroll
        for (int k = 0; k < 4; ++k) if (k < wv) waveOff += wsum[k];
        int total = wsum[0] + wsum[1] + wsum[2] + wsum[3];
        int r = waveOff + inc - cnt;
        int* sb = starts + b * TT;
        int* eb = ends + b * TT;
        unsigned int f = flags;
        while (f) {
            int k = __ffs(f) - 1;
            f &= f - 1;
            int t = t0 + k;
            sb[r + 1] = t;
            eb[r] = t + 2;                      // t <= 2046 -> t+2 <= TT
            ++r;
        }
        if (tid == 0) {
            sb[0] = 0;
            eb[total] = TT;
            counts[b] = total + 1;
        }
    }

    grid.sync();

    // ---- Phase 3: partitioned pool + zero + mask, grid-strided over work units.
    v4f zero = (v4f)(0.f);
    for (int u = blockIdx.x; u < TOTAL_UNITS; u += GRID) {
        if (u < ACTIVE_UNITS) {
            // active pool: 4 waves/unit, 1 wave per row, j in [0, 1024)
            int b    = u >> 8;                  // 256 units per batch
            int j    = (u & 255) * 4 + wv;
            int row  = b * TT + j;
            float* orow = out + (size_t)row * FF + lane * 8;

            v4f acc0 = zero;
            v4f acc1 = zero;
            if (j < counts[b]) {
                int s = __builtin_amdgcn_readfirstlane(starts[row]);
                int e = __builtin_amdgcn_readfirstlane(ends[row]);
                const float* xb   = x + (size_t)b * TT * FF + lane * 8;
                const float* wrow = wt + b * TT;
                float den = 0.f;
                for (int t = s; t < e; t += 4) {
                    int i1 = (t + 1 < e) ? t + 1 : t;
                    int i2 = (t + 2 < e) ? t + 2 : t;
                    int i3 = (t + 3 < e) ? t + 3 : t;
                    float w0 = wrow[t];
                    float w1 = (t + 1 < e) ? wrow[i1] : 0.f;
                    float w2 = (t + 2 < e) ? wrow[i2] : 0.f;
                    float w3 = (t + 3 < e) ? wrow[i3] : 0.f;
                    const v4f* p0 = (const v4f*)(xb + (size_t)t  * FF);
                    const v4f* p1 = (const v4f*)(xb + (size_t)i1 * FF);
                    const v4f* p2 = (const v4f*)(xb + (size_t)i2 * FF);
                    const v4f* p3 = (const v4f*)(xb + (size_t)i3 * FF);
                    v4f v00 = p0[0], v01 = p0[1];
                    v4f v10 = p1[0], v11 = p1[1];
                    v4f v20 = p2[0], v21 = p2[1];
                    v4f v30 = p3[0], v31 = p3[1];
                    acc0 += w0 * v00; acc1 += w0 * v01;
                    acc0 += w1 * v10; acc1 += w1 * v11;
                    acc0 += w2 * v20; acc1 += w2 * v21;
                    acc0 += w3 * v30; acc1 += w3 * v31;
                    den += w0 + w1 + w2 + w3;
                }
                float inv = 1.0f / fmaxf(den, 1e-6f);
                acc0 *= inv; acc1 *= inv;
            }
            __builtin_nontemporal_store(acc0, (v4f*)orow);
            __builtin_nontemporal_store(acc1, (v4f*)(orow + 4));
        } else if (u < ACTIVE_UNITS + ZERO_UNITS) {
            // zero region: rows j in [1024, 2048), 16 rows per unit
            int zb = u - ACTIVE_UNITS;          // [0, 1024)
            int b  = zb >> 6;                   // 64 units per batch
            int j0 = 1024 + (zb & 63) * 16;
            float* base = out + ((size_t)(b * TT + j0) * FF);
            v4f* dst = (v4f*)base + tid * 2;    // 16 rows x 512 f = 256 thr x 8 f
            __builtin_nontemporal_store(zero, dst);
            __builtin_nontemporal_store(zero, dst + 1);
        } else {
            // mask
            int idx = (u - ACTIVE_UNITS - ZERO_UNITS) * 256 + tid;  // [0, 8192)
            int maxc = 0;
#pragma unroll
            for (int i = 0; i < BB; ++i) maxc = max(maxc, counts[i]);
            float len0 = (float)min(seq_len[0], TT);
#pragma unroll
            for (int r = 0; r < 4; ++r) {
                int i = idx + r * 8192;         // [0, B*T)
                int b = i >> 11, t = i & (TT - 1);
                int nl = (int)((float)min(seq_len[b], TT) / len0 * (float)maxc);
                mask_out[i] = (t < nl) ? 1.0f : 0.0f;
            }
        }
    }
}

extern "C" void kernel_launch(void* const* d_in, const int* in_sizes, int n_in,
                              void* d_out, int out_size, void* d_ws, size_t ws_size,
                              hipStream_t stream) {
    const float* x       = (const float*)d_in[0];
    const float* w_aggr  = (const float*)d_in[1];
    const float* b_aggr  = (const float*)d_in[2];
    const int*   seq_len = (const int*)d_in[3];

    float* pooled = (float*)d_out;
    float* mask   = (float*)d_out + (size_t)BB * TT * FF;

    float* wt    = (float*)d_ws;
    int* starts  = (int*)((char*)d_ws + (size_t)BB * TT * 4);
    int* ends    = starts + BB * TT;
    int* counts  = ends + BB * TT;

    void* args[] = {(void*)&x, (void*)&w_aggr, (void*)&b_aggr, (void*)&seq_len,
                    (void*)&wt, (void*)&starts, (void*)&ends, (void*)&counts,
                    (void*)&pooled, (void*)&mask};
    hipLaunchCooperativeKernel(reinterpret_cast<void*>(fused_kernel),
                               dim3(GRID), dim3(256), args, 0, stream);
}

// Round 2
// 126.308 us; speedup vs baseline: 2.5646x; 2.5646x over previous
//
#include <hip/hip_runtime.h>
#include <math.h>

#define BB 16
#define TT 2048
#define FF 512

#define CHUNK  32              // t-positions per K1 block
#define NCHUNK (TT / CHUNK)    // 64 flag words per batch

#define ACTIVE_UNITS 4096      // 256 units/batch x 16, 4 waves/unit, rows j<1024
#define ZERO_UNITS   1024      // rows j in [1024,2048): always zero (counts <= 1024)
#define MASK_UNITS   32

typedef float v4f __attribute__((ext_vector_type(4)));

// K1: one block = 32 contiguous t of one batch (+2 halo rows recomputed).
// Computes wt (identical arithmetic to verified version) and a 32-bit valley
// flag word per chunk via ballot. No cross-block deps.
__global__ __launch_bounds__(256) void wtflag_kernel(const float* __restrict__ x,
                                                     const float* __restrict__ w,
                                                     const float* __restrict__ bias,
                                                     float* __restrict__ wt,
                                                     unsigned int* __restrict__ flags) {
    __shared__ float arr[CHUNK + 2];   // [0]=left halo, [1..32]=chunk, [33]=right halo
    int blk  = blockIdx.x;             // 16*64 = 1024 blocks
    int b    = blk >> 6;
    int c    = blk & 63;
    int t0   = c * CHUNK;
    int tid  = threadIdx.x;
    int wv   = tid >> 6;
    int lane = tid & 63;

    const float* wp = w + lane * 8;
    float4 w0 = *(const float4*)wp;
    float4 w1 = *(const float4*)(wp + 4);
    float bz = bias[0];

    // ---- main rows: wave wv handles t = t0 + wv*8 + i, i in [0,8) ----
    int rbase = b * TT + t0 + wv * 8;
    const float* xr0 = x + (size_t)rbase * FF + lane * 8;
    float sv[8];
#pragma unroll
    for (int i = 0; i < 8; ++i) {
        const float* xr = xr0 + (size_t)i * FF;
        float4 a0 = *(const float4*)xr;
        float4 a1 = *(const float4*)(xr + 4);
        sv[i] = a0.x * w0.x + a0.y * w0.y + a0.z * w0.z + a0.w * w0.w
              + a1.x * w1.x + a1.y * w1.y + a1.z * w1.z + a1.w * w1.w;
    }
#pragma unroll
    for (int i = 0; i < 8; ++i) {
        float s = sv[i];
#pragma unroll
        for (int off = 32; off > 0; off >>= 1) s += __shfl_xor(s, off, 64);
        float val = 1.0f / (1.0f + expf(-(s + bz)));
        if (lane == 0) {
            arr[1 + wv * 8 + i] = val;
            wt[rbase + i] = val;
        }
    }

    // ---- halo rows (recomputed, identical arithmetic; value only needed in LDS) ----
    if (wv == 0) {
        if (t0 > 0) {
            const float* xr = x + (size_t)(b * TT + t0 - 1) * FF + lane * 8;
            float4 a0 = *(const float4*)xr;
            float4 a1 = *(const float4*)(xr + 4);
            float s = a0.x * w0.x + a0.y * w0.y + a0.z * w0.z + a0.w * w0.w
                    + a1.x * w1.x + a1.y * w1.y + a1.z * w1.z + a1.w * w1.w;
#pragma unroll
            for (int off = 32; off > 0; off >>= 1) s += __shfl_xor(s, off, 64);
            if (lane == 0) arr[0] = 1.0f / (1.0f + expf(-(s + bz)));
        } else if (lane == 0) arr[0] = 0.f;      // unused (t=0 never valley)
    }
    if (wv == 3) {
        if (t0 + CHUNK < TT) {
            const float* xr = x + (size_t)(b * TT + t0 + CHUNK) * FF + lane * 8;
            float4 a0 = *(const float4*)xr;
            float4 a1 = *(const float4*)(xr + 4);
            float s = a0.x * w0.x + a0.y * w0.y + a0.z * w0.z + a0.w * w0.w
                    + a1.x * w1.x + a1.y * w1.y + a1.z * w1.z + a1.w * w1.w;
#pragma unroll
            for (int off = 32; off > 0; off >>= 1) s += __shfl_xor(s, off, 64);
            if (lane == 0) arr[CHUNK + 1] = 1.0f / (1.0f + expf(-(s + bz)));
        } else if (lane == 0) arr[CHUNK + 1] = 0.f;  // unused (t=T-1 never valley)
    }

    __syncthreads();

    // ---- valley flags for the 32 positions, wave 0 only ----
    if (tid < 64) {
        bool val = false;
        if (tid < CHUNK) {
            int t = t0 + tid;
            float cv = arr[1 + tid];
            float pv = arr[tid];
            float nv = arr[2 + tid];
            val = (t > 0) && (t < TT - 1) && (cv < pv) && (cv < nv);
        }
        unsigned long long bm = __ballot(val);
        if (tid == 0) flags[b * NCHUNK + c] = (unsigned int)bm;
    }
}

// K3: partitioned pool + zero + mask. Active waves reconstruct start/end from
// the 64 flag words of their batch (popc + wave scan + n-th set bit).
__global__ __launch_bounds__(256) void pool_kernel(const float* __restrict__ x,
                                                   const float* __restrict__ wt,
                                                   const unsigned int* __restrict__ flags,
                                                   const int* __restrict__ seq_len,
                                                   float* __restrict__ out,
                                                   float* __restrict__ mask_out) {
    int blk = blockIdx.x;
    int tid = threadIdx.x;
    v4f zero = (v4f)(0.f);

    if (blk >= ACTIVE_UNITS + ZERO_UNITS) {
        // ---- mask: compute counts[b] for all b from flags, then new_mask ----
        __shared__ int cnts_lds[BB];
        int s4 = 0;
#pragma unroll
        for (int q = 0; q < 4; ++q) s4 += __popc(flags[tid * 4 + q]);
#pragma unroll
        for (int off = 1; off < 16; off <<= 1) s4 += __shfl_xor(s4, off, 64);
        if ((tid & 15) == 0) cnts_lds[tid >> 4] = s4 + 1;   // counts = #valleys + 1
        __syncthreads();
        int maxc = 0;
#pragma unroll
        for (int i = 0; i < BB; ++i) maxc = max(maxc, cnts_lds[i]);
        float len0 = (float)min(seq_len[0], TT);
        int idx = (blk - ACTIVE_UNITS - ZERO_UNITS) * 256 + tid;  // [0, 8192)
#pragma unroll
        for (int r = 0; r < 4; ++r) {
            int i = idx + r * 8192;       // [0, B*T)
            int b = i >> 11, t = i & (TT - 1);
            int nl = (int)((float)min(seq_len[b], TT) / len0 * (float)maxc);
            mask_out[i] = (t < nl) ? 1.0f : 0.0f;
        }
        return;
    }

    if (blk >= ACTIVE_UNITS) {
        // ---- zero region: rows j in [1024, 2048), 16 rows per block ----
        int zb = blk - ACTIVE_UNITS;      // [0, 1024)
        int b  = zb >> 6;
        int j0 = 1024 + (zb & 63) * 16;
        float* base = out + ((size_t)(b * TT + j0) * FF);
        v4f* dst = (v4f*)base + tid * 2;
        __builtin_nontemporal_store(zero, dst);
        __builtin_nontemporal_store(zero, dst + 1);
        return;
    }

    // ---- active pool: 4 waves/block, 1 wave per row, j in [0, 1024) ----
    int b    = blk >> 8;
    int wv   = tid >> 6;
    int lane = tid & 63;
    int j    = (blk & 255) * 4 + wv;
    int row  = b * TT + j;
    float* orow = out + (size_t)row * FF + lane * 8;

    // reconstruct segment boundaries from flags
    const unsigned int* fb = flags + b * NCHUNK;
    unsigned int wd = fb[lane];           // word `lane` covers t in [lane*32, lane*32+32)
    int pc  = __popc(wd);
    int inc = pc;
#pragma unroll
    for (int off = 1; off < 64; off <<= 1) {
        int y = __shfl_up(inc, off, 64);
        if (lane >= off) inc += y;
    }
    int exc = inc - pc;                   // exclusive prefix of set bits
    int k   = __shfl(inc, 63, 64);        // total #valleys
    int cnt = k + 1;

    v4f acc0 = zero;
    v4f acc1 = zero;
    if (j < cnt) {
        // j-th set bit (1-indexed) -> valley position
        auto findv = [&](int jj) -> int {
            bool has = (exc < jj) && (jj <= exc + pc);
            unsigned long long m = __ballot(has);
            int ls = (int)(__ffsll(m) - 1);
            unsigned int wsel = __shfl(wd, ls, 64);
            int base = __shfl(exc, ls, 64);
            int need = jj - base;         // in [1, 32]
            for (int q = 1; q < need; ++q) wsel &= wsel - 1;
            return ls * 32 + (__ffs(wsel) - 1);
        };
        int s = (j == 0) ? 0  : findv(j);
        int e = (j == k) ? TT : findv(j + 1) + 2;
        s = __builtin_amdgcn_readfirstlane(s);
        e = __builtin_amdgcn_readfirstlane(e);

        const float* xb   = x + (size_t)b * TT * FF + lane * 8;
        const float* wrow = wt + b * TT;
        float den = 0.f;
        for (int t = s; t < e; t += 4) {
            int i1 = (t + 1 < e) ? t + 1 : t;
            int i2 = (t + 2 < e) ? t + 2 : t;
            int i3 = (t + 3 < e) ? t + 3 : t;
            float w0 = wrow[t];
            float w1 = (t + 1 < e) ? wrow[i1] : 0.f;
            float w2 = (t + 2 < e) ? wrow[i2] : 0.f;
            float w3 = (t + 3 < e) ? wrow[i3] : 0.f;
            const v4f* p0 = (const v4f*)(xb + (size_t)t  * FF);
            const v4f* p1 = (const v4f*)(xb + (size_t)i1 * FF);
            const v4f* p2 = (const v4f*)(xb + (size_t)i2 * FF);
            const v4f* p3 = (const v4f*)(xb + (size_t)i3 * FF);
            v4f v00 = p0[0], v01 = p0[1];
            v4f v10 = p1[0], v11 = p1[1];
            v4f v20 = p2[0], v21 = p2[1];
            v4f v30 = p3[0], v31 = p3[1];
            acc0 += w0 * v00; acc1 += w0 * v01;
            acc0 += w1 * v10; acc1 += w1 * v11;
            acc0 += w2 * v20; acc1 += w2 * v21;
            acc0 += w3 * v30; acc1 += w3 * v31;
            den += w0 + w1 + w2 + w3;
        }
        float inv = 1.0f / fmaxf(den, 1e-6f);
        acc0 *= inv; acc1 *= inv;
    }
    __builtin_nontemporal_store(acc0, (v4f*)orow);
    __builtin_nontemporal_store(acc1, (v4f*)(orow + 4));
}

extern "C" void kernel_launch(void* const* d_in, const int* in_sizes, int n_in,
                              void* d_out, int out_size, void* d_ws, size_t ws_size,
                              hipStream_t stream) {
    const float* x       = (const float*)d_in[0];
    const float* w_aggr  = (const float*)d_in[1];
    const float* b_aggr  = (const float*)d_in[2];
    const int*   seq_len = (const int*)d_in[3];

    float* pooled = (float*)d_out;
    float* mask   = (float*)d_out + (size_t)BB * TT * FF;

    float*        wt    = (float*)d_ws;
    unsigned int* flags = (unsigned int*)((char*)d_ws + (size_t)BB * TT * 4);

    wtflag_kernel<<<BB * NCHUNK, 256, 0, stream>>>(x, w_aggr, b_aggr, wt, flags);
    pool_kernel<<<ACTIVE_UNITS + ZERO_UNITS + MASK_UNITS, 256, 0, stream>>>(
        x, wt, flags, seq_len, pooled, mask);
}